// Round 1
// baseline (8420.811 us; speedup 1.0000x reference)
//
#include <hip/hip_runtime.h>
#include <math.h>

#define NN 100000
#define DD 128

// ---------------- degree ----------------
__global__ void deg_kernel(const int* __restrict__ dst, int E, float* __restrict__ deg) {
    int i = blockIdx.x * blockDim.x + threadIdx.x;
    if (i < E) atomicAdd(&deg[dst[i]], 1.0f);
}

__global__ void dinv_kernel(float* __restrict__ dinv, int n) {
    int i = blockIdx.x * blockDim.x + threadIdx.x;
    if (i < n) {
        float d = dinv[i] + 1.0f;   // +1 for self-loop
        dinv[i] = rsqrtf(d);
    }
}

// ---------------- GEMM + norm fuse ----------------
// G[i]   = (X @ W)[i] * dinv[i]          (pre-normalized messages)
// Acc[i] = G[i] * dinv[i]                (self-loop init of the aggregator)
// X and Acc may alias: each block reads only its own 64 rows into LDS
// before writing those same rows in the epilogue.
__global__ __launch_bounds__(256) void gemm_norm_kernel(
    const float* __restrict__ X, const float* __restrict__ W,
    const float* __restrict__ dinv, float* __restrict__ G, float* __restrict__ Acc)
{
    __shared__ float ws[128 * 128];     // 64 KB
    __shared__ float xs[64][132];       // 33 KB, +4 pad to break bank stride

    const int tid  = threadIdx.x;
    const int base = blockIdx.x * 64;

    // stage W (16384 floats = 4096 float4)
    {
        const float4* W4 = (const float4*)W;
        float4* S4 = (float4*)ws;
        #pragma unroll
        for (int it = 0; it < 16; ++it) S4[tid + it * 256] = W4[tid + it * 256];
    }
    // stage X tile (64 x 128)
    #pragma unroll
    for (int it = 0; it < 8; ++it) {
        int lin = tid + it * 256;          // 0..2047
        int r = lin >> 5;
        int c = (lin & 31) << 2;
        int row = base + r;
        float4 v = make_float4(0.f, 0.f, 0.f, 0.f);
        if (row < NN) v = *(const float4*)&X[row * DD + c];
        *(float4*)&xs[r][c] = v;
    }
    __syncthreads();

    const int cg = tid & 7;        // col group: cols cg*4 + s*32
    const int rp = tid >> 3;       // 0..31
    const int r0 = rp * 2, r1 = r0 + 1;

    float acc0[4][4] = {{0.f}};
    float acc1[4][4] = {{0.f}};

    #pragma unroll 4
    for (int k = 0; k < 128; ++k) {
        float a0 = xs[r0][k];
        float a1 = xs[r1][k];
        #pragma unroll
        for (int s = 0; s < 4; ++s) {
            const float4 wv = *(const float4*)&ws[k * 128 + cg * 4 + s * 32];
            acc0[s][0] += a0 * wv.x; acc0[s][1] += a0 * wv.y;
            acc0[s][2] += a0 * wv.z; acc0[s][3] += a0 * wv.w;
            acc1[s][0] += a1 * wv.x; acc1[s][1] += a1 * wv.y;
            acc1[s][2] += a1 * wv.z; acc1[s][3] += a1 * wv.w;
        }
    }

    int row0 = base + r0;
    if (row0 < NN) {
        float di = dinv[row0], di2 = di * di;
        #pragma unroll
        for (int s = 0; s < 4; ++s) {
            float4 gv, av;
            gv.x = acc0[s][0] * di;  gv.y = acc0[s][1] * di;
            gv.z = acc0[s][2] * di;  gv.w = acc0[s][3] * di;
            av.x = acc0[s][0] * di2; av.y = acc0[s][1] * di2;
            av.z = acc0[s][2] * di2; av.w = acc0[s][3] * di2;
            *(float4*)&G[row0 * DD + cg * 4 + s * 32]   = gv;
            *(float4*)&Acc[row0 * DD + cg * 4 + s * 32] = av;
        }
    }
    int row1 = base + r1;
    if (row1 < NN) {
        float di = dinv[row1], di2 = di * di;
        #pragma unroll
        for (int s = 0; s < 4; ++s) {
            float4 gv, av;
            gv.x = acc1[s][0] * di;  gv.y = acc1[s][1] * di;
            gv.z = acc1[s][2] * di;  gv.w = acc1[s][3] * di;
            av.x = acc1[s][0] * di2; av.y = acc1[s][1] * di2;
            av.z = acc1[s][2] * di2; av.w = acc1[s][3] * di2;
            *(float4*)&G[row1 * DD + cg * 4 + s * 32]   = gv;
            *(float4*)&Acc[row1 * DD + cg * 4 + s * 32] = av;
        }
    }
}

// ---------------- edge scatter ----------------
// 32 lanes per edge, float4 per lane: out[dst] += g[src] * dinv[dst]
__global__ void scatter_kernel(const float* __restrict__ g, const float* __restrict__ dinv,
                               const int* __restrict__ src, const int* __restrict__ dst,
                               float* __restrict__ out, int E)
{
    int t = blockIdx.x * 256 + threadIdx.x;
    int e = t >> 5;
    if (e >= E) return;
    int j = (t & 31) << 2;
    int s = src[e];
    int d = dst[e];
    float w = dinv[d];
    const float4 v = *(const float4*)&g[s * DD + j];
    float* o = &out[d * DD + j];
    atomicAdd(o + 0, v.x * w);
    atomicAdd(o + 1, v.y * w);
    atomicAdd(o + 2, v.z * w);
    atomicAdd(o + 3, v.w * w);
}

// ---------------- bias + relu (in place ok) ----------------
__global__ void bias_relu_kernel(const float* __restrict__ acc, const float* __restrict__ b,
                                 float* __restrict__ outp, int n4)
{
    int i = blockIdx.x * blockDim.x + threadIdx.x;
    if (i >= n4) return;
    float4 v = ((const float4*)acc)[i];
    int c = (i & 31) << 2;
    const float4 bb = *(const float4*)&b[c];
    v.x = fmaxf(v.x + bb.x, 0.f);
    v.y = fmaxf(v.y + bb.y, 0.f);
    v.z = fmaxf(v.z + bb.z, 0.f);
    v.w = fmaxf(v.w + bb.w, 0.f);
    ((float4*)outp)[i] = v;
}

extern "C" void kernel_launch(void* const* d_in, const int* in_sizes, int n_in,
                              void* d_out, int out_size, void* d_ws, size_t ws_size,
                              hipStream_t stream)
{
    const float* x  = (const float*)d_in[0];
    const float* W1 = (const float*)d_in[1];
    const float* b1 = (const float*)d_in[2];
    const float* W2 = (const float*)d_in[3];
    const float* b2 = (const float*)d_in[4];
    const float* W3 = (const float*)d_in[5];
    const float* b3 = (const float*)d_in[6];
    const int*   ei = (const int*)d_in[7];

    const int E = in_sizes[7] / 2;          // 1,600,000
    const int* src = ei;
    const int* dst = ei + E;

    float* out = (float*)d_out;             // aggregator + activation ping (in place)

    char* wsb = (char*)d_ws;
    float* dinv = (float*)wsb;                       // N floats
    float* g    = (float*)(wsb + (1 << 19));         // N*D floats (51.2 MB)

    // ---- degree / dinv ----
    hipMemsetAsync(dinv, 0, NN * sizeof(float), stream);
    deg_kernel<<<(E + 255) / 256, 256, 0, stream>>>(dst, E, dinv);
    dinv_kernel<<<(NN + 255) / 256, 256, 0, stream>>>(dinv, NN);

    const int gemm_grid    = (NN + 63) / 64;         // 1563
    const int scatter_grid = (E * 32 + 255) / 256;   // 200,000
    const int n4           = NN * DD / 4;            // 3,200,000
    const int relu_grid    = (n4 + 255) / 256;

    // ---- layer 1 ----
    gemm_norm_kernel<<<gemm_grid, 256, 0, stream>>>(x, W1, dinv, g, out);
    scatter_kernel<<<scatter_grid, 256, 0, stream>>>(g, dinv, src, dst, out, E);
    bias_relu_kernel<<<relu_grid, 256, 0, stream>>>(out, b1, out, n4);

    // ---- layer 2 ----
    gemm_norm_kernel<<<gemm_grid, 256, 0, stream>>>(out, W2, dinv, g, out);
    scatter_kernel<<<scatter_grid, 256, 0, stream>>>(g, dinv, src, dst, out, E);
    bias_relu_kernel<<<relu_grid, 256, 0, stream>>>(out, b2, out, n4);

    // ---- layer 3 ----
    gemm_norm_kernel<<<gemm_grid, 256, 0, stream>>>(out, W3, dinv, g, out);
    scatter_kernel<<<scatter_grid, 256, 0, stream>>>(g, dinv, src, dst, out, E);
    bias_relu_kernel<<<relu_grid, 256, 0, stream>>>(out, b3, out, n4);
}

// Round 2
// 792.738 us; speedup vs baseline: 10.6224x; 10.6224x over previous
//
#include <hip/hip_runtime.h>
#include <math.h>

#define NN 100000
#define DD 128
#define SCAN_CHUNK 2048

// ---------------- degree histogram (int) ----------------
__global__ void hist_kernel(const int* __restrict__ dst, int E, int* __restrict__ deg) {
    int i = blockIdx.x * blockDim.x + threadIdx.x;
    if (i < E) atomicAdd(&deg[dst[i]], 1);
}

// ---------------- dinv = rsqrt(indeg + 1) ----------------
__global__ void dinv_kernel(const int* __restrict__ deg, float* __restrict__ dinv, int n) {
    int i = blockIdx.x * blockDim.x + threadIdx.x;
    if (i < n) dinv[i] = rsqrtf((float)deg[i] + 1.0f);
}

// ---------------- scan part 1: per-chunk sums ----------------
__global__ __launch_bounds__(256) void scan1_kernel(const int* __restrict__ deg,
                                                    int* __restrict__ chunkSum, int n) {
    __shared__ int lds[256];
    int tid = threadIdx.x;
    int base = blockIdx.x * SCAN_CHUNK + tid * 8;
    int s = 0;
    #pragma unroll
    for (int j = 0; j < 8; ++j) {
        int idx = base + j;
        if (idx < n) s += deg[idx];
    }
    lds[tid] = s;
    __syncthreads();
    for (int d = 128; d > 0; d >>= 1) {
        if (tid < d) lds[tid] += lds[tid + d];
        __syncthreads();
    }
    if (tid == 0) chunkSum[blockIdx.x] = lds[0];
}

// ---------------- scan part 2: scan chunk sums (1 block) ----------------
__global__ void scan2_kernel(int* __restrict__ chunkSum, int* __restrict__ chunkOff,
                             int nb, int* __restrict__ offsets /* writes offsets[NN]=total */) {
    __shared__ int lds[512];
    int tid = threadIdx.x;
    if (tid < nb) lds[tid] = chunkSum[tid];
    __syncthreads();
    if (tid == 0) {
        int run = 0;
        for (int i = 0; i < nb; ++i) {
            int v = lds[i];
            lds[i] = run;
            run += v;
        }
        offsets[NN] = run;
    }
    __syncthreads();
    if (tid < nb) chunkOff[tid] = lds[tid];
}

// ---------------- scan part 3: per-chunk exclusive scan ----------------
__global__ __launch_bounds__(256) void scan3_kernel(const int* __restrict__ deg,
                                                    const int* __restrict__ chunkOff,
                                                    int* __restrict__ offsets, int n) {
    __shared__ int lds[256];
    int tid = threadIdx.x;
    int base = blockIdx.x * SCAN_CHUNK + tid * 8;
    int v[8];
    int tsum = 0;
    #pragma unroll
    for (int j = 0; j < 8; ++j) {
        int idx = base + j;
        v[j] = (idx < n) ? deg[idx] : 0;
        tsum += v[j];
    }
    lds[tid] = tsum;
    __syncthreads();
    // Hillis-Steele inclusive scan over 256 thread sums
    for (int d = 1; d < 256; d <<= 1) {
        int t = (tid >= d) ? lds[tid - d] : 0;
        __syncthreads();
        lds[tid] += t;
        __syncthreads();
    }
    int excl = lds[tid] - tsum;
    int off0 = chunkOff[blockIdx.x] + excl;
    int run = 0;
    #pragma unroll
    for (int j = 0; j < 8; ++j) {
        int idx = base + j;
        if (idx < n) offsets[idx] = off0 + run;
        run += v[j];
    }
}

// ---------------- CSR fill (destroys deg) ----------------
__global__ void fill_kernel(const int* __restrict__ src, const int* __restrict__ dst, int E,
                            const int* __restrict__ offsets, int* __restrict__ deg,
                            int* __restrict__ csr) {
    int e = blockIdx.x * blockDim.x + threadIdx.x;
    if (e >= E) return;
    int d = dst[e];
    int old = atomicSub(&deg[d], 1);          // old in [1, deg]
    csr[offsets[d + 1] - old] = src[e];
}

// ---------------- GEMM + src-norm fuse: g = (X @ W) * dinv[row] ----------------
__global__ __launch_bounds__(256) void gemm_norm_kernel(
    const float* __restrict__ X, const float* __restrict__ W,
    const float* __restrict__ dinv, float* __restrict__ G)
{
    __shared__ float ws[128 * 128];     // 64 KB
    __shared__ float xs[64][132];       // 33 KB

    const int tid  = threadIdx.x;
    const int base = blockIdx.x * 64;

    {
        const float4* W4 = (const float4*)W;
        float4* S4 = (float4*)ws;
        #pragma unroll
        for (int it = 0; it < 16; ++it) S4[tid + it * 256] = W4[tid + it * 256];
    }
    #pragma unroll
    for (int it = 0; it < 8; ++it) {
        int lin = tid + it * 256;
        int r = lin >> 5;
        int c = (lin & 31) << 2;
        int row = base + r;
        float4 v = make_float4(0.f, 0.f, 0.f, 0.f);
        if (row < NN) v = *(const float4*)&X[row * DD + c];
        *(float4*)&xs[r][c] = v;
    }
    __syncthreads();

    const int cg = tid & 7;
    const int rp = tid >> 3;
    const int r0 = rp * 2, r1 = r0 + 1;

    float acc0[4][4] = {{0.f}};
    float acc1[4][4] = {{0.f}};

    #pragma unroll 4
    for (int k = 0; k < 128; ++k) {
        float a0 = xs[r0][k];
        float a1 = xs[r1][k];
        #pragma unroll
        for (int s = 0; s < 4; ++s) {
            const float4 wv = *(const float4*)&ws[k * 128 + cg * 4 + s * 32];
            acc0[s][0] += a0 * wv.x; acc0[s][1] += a0 * wv.y;
            acc0[s][2] += a0 * wv.z; acc0[s][3] += a0 * wv.w;
            acc1[s][0] += a1 * wv.x; acc1[s][1] += a1 * wv.y;
            acc1[s][2] += a1 * wv.z; acc1[s][3] += a1 * wv.w;
        }
    }

    int row0 = base + r0;
    if (row0 < NN) {
        float di = dinv[row0];
        #pragma unroll
        for (int s = 0; s < 4; ++s) {
            float4 gv;
            gv.x = acc0[s][0] * di;  gv.y = acc0[s][1] * di;
            gv.z = acc0[s][2] * di;  gv.w = acc0[s][3] * di;
            *(float4*)&G[row0 * DD + cg * 4 + s * 32] = gv;
        }
    }
    int row1 = base + r1;
    if (row1 < NN) {
        float di = dinv[row1];
        #pragma unroll
        for (int s = 0; s < 4; ++s) {
            float4 gv;
            gv.x = acc1[s][0] * di;  gv.y = acc1[s][1] * di;
            gv.z = acc1[s][2] * di;  gv.w = acc1[s][3] * di;
            *(float4*)&G[row1 * DD + cg * 4 + s * 32] = gv;
        }
    }
}

// ---------------- gather-aggregate + bias + relu ----------------
// one wave per dst node; lane holds float2 slice of the 128-wide row
// out[d] = relu( dinv[d] * (sum_{e in in(d)} g[src_e] + g[d]) + b )
__global__ __launch_bounds__(256) void agg_kernel(
    const float* __restrict__ g, const float* __restrict__ dinv,
    const int* __restrict__ off, const int* __restrict__ csr,
    const float* __restrict__ bias, float* __restrict__ out)
{
    int node = (blockIdx.x * 256 + threadIdx.x) >> 6;
    if (node >= NN) return;
    int lane = threadIdx.x & 63;
    const float2* __restrict__ g2 = (const float2*)g;

    float2 acc = g2[node * 64 + lane];   // self-loop message
    int e = off[node], end = off[node + 1];

    for (; e + 4 <= end; e += 4) {
        int s0 = csr[e], s1 = csr[e + 1], s2 = csr[e + 2], s3 = csr[e + 3];
        float2 v0 = g2[s0 * 64 + lane];
        float2 v1 = g2[s1 * 64 + lane];
        float2 v2 = g2[s2 * 64 + lane];
        float2 v3 = g2[s3 * 64 + lane];
        acc.x += (v0.x + v1.x) + (v2.x + v3.x);
        acc.y += (v0.y + v1.y) + (v2.y + v3.y);
    }
    for (; e < end; ++e) {
        float2 v = g2[csr[e] * 64 + lane];
        acc.x += v.x; acc.y += v.y;
    }

    float di = dinv[node];
    float2 bb = ((const float2*)bias)[lane];
    float2 o;
    o.x = fmaxf(fmaf(acc.x, di, bb.x), 0.f);
    o.y = fmaxf(fmaf(acc.y, di, bb.y), 0.f);
    ((float2*)out)[node * 64 + lane] = o;
}

extern "C" void kernel_launch(void* const* d_in, const int* in_sizes, int n_in,
                              void* d_out, int out_size, void* d_ws, size_t ws_size,
                              hipStream_t stream)
{
    const float* x  = (const float*)d_in[0];
    const float* W1 = (const float*)d_in[1];
    const float* b1 = (const float*)d_in[2];
    const float* W2 = (const float*)d_in[3];
    const float* b2 = (const float*)d_in[4];
    const float* W3 = (const float*)d_in[5];
    const float* b3 = (const float*)d_in[6];
    const int*   ei = (const int*)d_in[7];

    const int E = in_sizes[7] / 2;          // 1,600,000
    const int* src = ei;
    const int* dst = ei + E;

    float* out = (float*)d_out;

    // ---- workspace layout ----
    char* wsb = (char*)d_ws;
    size_t p = 0;
    int* deg      = (int*)(wsb + p); p += ((size_t)NN * 4 + 1023) & ~1023ull;
    int* offsets  = (int*)(wsb + p); p += ((size_t)(NN + 1) * 4 + 1023) & ~1023ull;
    int* chunkSum = (int*)(wsb + p); p += 4096;
    int* chunkOff = (int*)(wsb + p); p += 4096;
    int* csr      = (int*)(wsb + p); p += ((size_t)E * 4 + 1023) & ~1023ull;
    float* dinv   = (float*)(wsb + p); p += ((size_t)NN * 4 + 1023) & ~1023ull;
    float* g      = (float*)(wsb + p); p += (size_t)NN * DD * 4;

    const int NB = (NN + SCAN_CHUNK - 1) / SCAN_CHUNK;   // 49

    // ---- CSR build + dinv ----
    hipMemsetAsync(deg, 0, (size_t)NN * 4, stream);
    hist_kernel<<<(E + 255) / 256, 256, 0, stream>>>(dst, E, deg);
    dinv_kernel<<<(NN + 255) / 256, 256, 0, stream>>>(deg, dinv, NN);
    scan1_kernel<<<NB, 256, 0, stream>>>(deg, chunkSum, NN);
    scan2_kernel<<<1, 512, 0, stream>>>(chunkSum, chunkOff, NB, offsets);
    scan3_kernel<<<NB, 256, 0, stream>>>(deg, chunkOff, offsets, NN);
    fill_kernel<<<(E + 255) / 256, 256, 0, stream>>>(src, dst, E, offsets, deg, csr);

    const int gemm_grid = (NN + 63) / 64;                 // 1563
    const int agg_grid  = ((size_t)NN * 64 + 255) / 256;  // 25000

    // ---- layer 1 ----
    gemm_norm_kernel<<<gemm_grid, 256, 0, stream>>>(x, W1, dinv, g);
    agg_kernel<<<agg_grid, 256, 0, stream>>>(g, dinv, offsets, csr, b1, out);
    // ---- layer 2 ----
    gemm_norm_kernel<<<gemm_grid, 256, 0, stream>>>(out, W2, dinv, g);
    agg_kernel<<<agg_grid, 256, 0, stream>>>(g, dinv, offsets, csr, b2, out);
    // ---- layer 3 ----
    gemm_norm_kernel<<<gemm_grid, 256, 0, stream>>>(out, W3, dinv, g);
    agg_kernel<<<agg_grid, 256, 0, stream>>>(g, dinv, offsets, csr, b3, out);
}

// Round 3
// 659.310 us; speedup vs baseline: 12.7722x; 1.2024x over previous
//
#include <hip/hip_runtime.h>
#include <hip/hip_fp16.h>
#include <math.h>

#define NN 100000
#define DD 128
#define SCAN_CHUNK 2048

// ---------------- degree histogram (int) ----------------
__global__ void hist_kernel(const int* __restrict__ dst, int E, int* __restrict__ deg) {
    int i = blockIdx.x * blockDim.x + threadIdx.x;
    if (i < E) atomicAdd(&deg[dst[i]], 1);
}

// ---------------- dinv = rsqrt(indeg + 1) ----------------
__global__ void dinv_kernel(const int* __restrict__ deg, float* __restrict__ dinv, int n) {
    int i = blockIdx.x * blockDim.x + threadIdx.x;
    if (i < n) dinv[i] = rsqrtf((float)deg[i] + 1.0f);
}

// ---------------- scan part 1: per-chunk sums ----------------
__global__ __launch_bounds__(256) void scan1_kernel(const int* __restrict__ deg,
                                                    int* __restrict__ chunkSum, int n) {
    __shared__ int lds[256];
    int tid = threadIdx.x;
    int base = blockIdx.x * SCAN_CHUNK + tid * 8;
    int s = 0;
    #pragma unroll
    for (int j = 0; j < 8; ++j) {
        int idx = base + j;
        if (idx < n) s += deg[idx];
    }
    lds[tid] = s;
    __syncthreads();
    for (int d = 128; d > 0; d >>= 1) {
        if (tid < d) lds[tid] += lds[tid + d];
        __syncthreads();
    }
    if (tid == 0) chunkSum[blockIdx.x] = lds[0];
}

// ---------------- scan part 2: scan chunk sums (1 block) ----------------
__global__ void scan2_kernel(int* __restrict__ chunkSum, int* __restrict__ chunkOff,
                             int nb, int* __restrict__ offsets) {
    __shared__ int lds[512];
    int tid = threadIdx.x;
    if (tid < nb) lds[tid] = chunkSum[tid];
    __syncthreads();
    if (tid == 0) {
        int run = 0;
        for (int i = 0; i < nb; ++i) {
            int v = lds[i];
            lds[i] = run;
            run += v;
        }
        offsets[NN] = run;
    }
    __syncthreads();
    if (tid < nb) chunkOff[tid] = lds[tid];
}

// ---------------- scan part 3: per-chunk exclusive scan ----------------
__global__ __launch_bounds__(256) void scan3_kernel(const int* __restrict__ deg,
                                                    const int* __restrict__ chunkOff,
                                                    int* __restrict__ offsets, int n) {
    __shared__ int lds[256];
    int tid = threadIdx.x;
    int base = blockIdx.x * SCAN_CHUNK + tid * 8;
    int v[8];
    int tsum = 0;
    #pragma unroll
    for (int j = 0; j < 8; ++j) {
        int idx = base + j;
        v[j] = (idx < n) ? deg[idx] : 0;
        tsum += v[j];
    }
    lds[tid] = tsum;
    __syncthreads();
    for (int d = 1; d < 256; d <<= 1) {
        int t = (tid >= d) ? lds[tid - d] : 0;
        __syncthreads();
        lds[tid] += t;
        __syncthreads();
    }
    int excl = lds[tid] - tsum;
    int off0 = chunkOff[blockIdx.x] + excl;
    int run = 0;
    #pragma unroll
    for (int j = 0; j < 8; ++j) {
        int idx = base + j;
        if (idx < n) offsets[idx] = off0 + run;
        run += v[j];
    }
}

// ---------------- CSR fill (destroys deg) ----------------
__global__ void fill_kernel(const int* __restrict__ src, const int* __restrict__ dst, int E,
                            const int* __restrict__ offsets, int* __restrict__ deg,
                            int* __restrict__ csr) {
    int e = blockIdx.x * blockDim.x + threadIdx.x;
    if (e >= E) return;
    int d = dst[e];
    int old = atomicSub(&deg[d], 1);
    csr[offsets[d + 1] - old] = src[e];
}

// ---------------- GEMM + src-norm fuse: g = fp16((X @ W) * dinv[row]) ----------------
// 128-row tile, 256 threads; each thread: 4 rows x 16 cols.
// LDS: W 64KB + X 68.1KB (pad 133 -> conflict-free b32 column reads).
__global__ __launch_bounds__(256) void gemm_norm_kernel(
    const float* __restrict__ X, const float* __restrict__ W,
    const float* __restrict__ dinv, __half* __restrict__ G)
{
    __shared__ float ws[128 * 128];     // 64 KB
    __shared__ float xs[128][133];      // 68.1 KB

    const int tid  = threadIdx.x;
    const int base = blockIdx.x * 128;

    // stage W (16384 floats = 4096 float4)
    {
        const float4* W4 = (const float4*)W;
        float4* S4 = (float4*)ws;
        #pragma unroll
        for (int it = 0; it < 16; ++it) S4[tid + it * 256] = W4[tid + it * 256];
    }
    // stage X tile (128 x 128), scalar LDS writes due to pad
    #pragma unroll
    for (int it = 0; it < 16; ++it) {
        int lin = tid + it * 256;          // 0..4095
        int r = lin >> 5;
        int c = (lin & 31) << 2;
        int row = base + r;
        float4 v = make_float4(0.f, 0.f, 0.f, 0.f);
        if (row < NN) v = *(const float4*)&X[row * DD + c];
        xs[r][c]     = v.x;
        xs[r][c + 1] = v.y;
        xs[r][c + 2] = v.z;
        xs[r][c + 3] = v.w;
    }
    __syncthreads();

    const int cg = tid & 7;        // cols cg*4 + s*32
    const int rp = tid >> 3;       // 0..31
    const int r0 = rp * 4;

    float acc[4][4][4];            // [row][s][col]
    #pragma unroll
    for (int r = 0; r < 4; ++r)
        #pragma unroll
        for (int s = 0; s < 4; ++s)
            #pragma unroll
            for (int c = 0; c < 4; ++c) acc[r][s][c] = 0.f;

    #pragma unroll 4
    for (int k = 0; k < 128; ++k) {
        float a0 = xs[r0 + 0][k];
        float a1 = xs[r0 + 1][k];
        float a2 = xs[r0 + 2][k];
        float a3 = xs[r0 + 3][k];
        #pragma unroll
        for (int s = 0; s < 4; ++s) {
            const float4 wv = *(const float4*)&ws[k * 128 + cg * 4 + s * 32];
            acc[0][s][0] += a0 * wv.x; acc[0][s][1] += a0 * wv.y;
            acc[0][s][2] += a0 * wv.z; acc[0][s][3] += a0 * wv.w;
            acc[1][s][0] += a1 * wv.x; acc[1][s][1] += a1 * wv.y;
            acc[1][s][2] += a1 * wv.z; acc[1][s][3] += a1 * wv.w;
            acc[2][s][0] += a2 * wv.x; acc[2][s][1] += a2 * wv.y;
            acc[2][s][2] += a2 * wv.z; acc[2][s][3] += a2 * wv.w;
            acc[3][s][0] += a3 * wv.x; acc[3][s][1] += a3 * wv.y;
            acc[3][s][2] += a3 * wv.z; acc[3][s][3] += a3 * wv.w;
        }
    }

    #pragma unroll
    for (int r = 0; r < 4; ++r) {
        int row = base + r0 + r;
        if (row < NN) {
            float di = dinv[row];
            #pragma unroll
            for (int s = 0; s < 4; ++s) {
                __half2 h01 = __floats2half2_rn(acc[r][s][0] * di, acc[r][s][1] * di);
                __half2 h23 = __floats2half2_rn(acc[r][s][2] * di, acc[r][s][3] * di);
                __half2* gp = (__half2*)&G[row * DD + cg * 4 + s * 32];
                gp[0] = h01;
                gp[1] = h23;
            }
        }
    }
}

// ---------------- gather-aggregate + bias + relu ----------------
// one wave per dst node; lane holds half2 slice (2 cols) of the 128-wide row
__global__ __launch_bounds__(256) void agg_kernel(
    const __half* __restrict__ g, const float* __restrict__ dinv,
    const int* __restrict__ off, const int* __restrict__ csr,
    const float* __restrict__ bias, float* __restrict__ out)
{
    int node = (blockIdx.x * 256 + threadIdx.x) >> 6;
    if (node >= NN) return;
    int lane = threadIdx.x & 63;
    const __half2* __restrict__ g2 = (const __half2*)g;

    float2 acc = __half22float2(g2[node * 64 + lane]);   // self-loop message
    int e = off[node], end = off[node + 1];

    for (; e + 4 <= end; e += 4) {
        int s0 = csr[e], s1 = csr[e + 1], s2 = csr[e + 2], s3 = csr[e + 3];
        float2 v0 = __half22float2(g2[s0 * 64 + lane]);
        float2 v1 = __half22float2(g2[s1 * 64 + lane]);
        float2 v2 = __half22float2(g2[s2 * 64 + lane]);
        float2 v3 = __half22float2(g2[s3 * 64 + lane]);
        acc.x += (v0.x + v1.x) + (v2.x + v3.x);
        acc.y += (v0.y + v1.y) + (v2.y + v3.y);
    }
    for (; e < end; ++e) {
        float2 v = __half22float2(g2[csr[e] * 64 + lane]);
        acc.x += v.x; acc.y += v.y;
    }

    float di = dinv[node];
    float2 bb = ((const float2*)bias)[lane];
    float2 o;
    o.x = fmaxf(fmaf(acc.x, di, bb.x), 0.f);
    o.y = fmaxf(fmaf(acc.y, di, bb.y), 0.f);
    ((float2*)out)[node * 64 + lane] = o;
}

extern "C" void kernel_launch(void* const* d_in, const int* in_sizes, int n_in,
                              void* d_out, int out_size, void* d_ws, size_t ws_size,
                              hipStream_t stream)
{
    const float* x  = (const float*)d_in[0];
    const float* W1 = (const float*)d_in[1];
    const float* b1 = (const float*)d_in[2];
    const float* W2 = (const float*)d_in[3];
    const float* b2 = (const float*)d_in[4];
    const float* W3 = (const float*)d_in[5];
    const float* b3 = (const float*)d_in[6];
    const int*   ei = (const int*)d_in[7];

    const int E = in_sizes[7] / 2;          // 1,600,000
    const int* src = ei;
    const int* dst = ei + E;

    float* out = (float*)d_out;

    // ---- workspace layout ----
    char* wsb = (char*)d_ws;
    size_t p = 0;
    int* deg      = (int*)(wsb + p); p += ((size_t)NN * 4 + 1023) & ~1023ull;
    int* offsets  = (int*)(wsb + p); p += ((size_t)(NN + 1) * 4 + 1023) & ~1023ull;
    int* chunkSum = (int*)(wsb + p); p += 4096;
    int* chunkOff = (int*)(wsb + p); p += 4096;
    int* csr      = (int*)(wsb + p); p += ((size_t)E * 4 + 1023) & ~1023ull;
    float* dinv   = (float*)(wsb + p); p += ((size_t)NN * 4 + 1023) & ~1023ull;
    __half* g     = (__half*)(wsb + p); p += (size_t)NN * DD * 2;

    const int NB = (NN + SCAN_CHUNK - 1) / SCAN_CHUNK;   // 49

    // ---- CSR build + dinv ----
    hipMemsetAsync(deg, 0, (size_t)NN * 4, stream);
    hist_kernel<<<(E + 255) / 256, 256, 0, stream>>>(dst, E, deg);
    dinv_kernel<<<(NN + 255) / 256, 256, 0, stream>>>(deg, dinv, NN);
    scan1_kernel<<<NB, 256, 0, stream>>>(deg, chunkSum, NN);
    scan2_kernel<<<1, 512, 0, stream>>>(chunkSum, chunkOff, NB, offsets);
    scan3_kernel<<<NB, 256, 0, stream>>>(deg, chunkOff, offsets, NN);
    fill_kernel<<<(E + 255) / 256, 256, 0, stream>>>(src, dst, E, offsets, deg, csr);

    const int gemm_grid = (NN + 127) / 128;               // 782
    const int agg_grid  = ((size_t)NN * 64 + 255) / 256;  // 25000

    // ---- layer 1 ----
    gemm_norm_kernel<<<gemm_grid, 256, 0, stream>>>(x, W1, dinv, g);
    agg_kernel<<<agg_grid, 256, 0, stream>>>(g, dinv, offsets, csr, b1, out);
    // ---- layer 2 ----
    gemm_norm_kernel<<<gemm_grid, 256, 0, stream>>>(out, W2, dinv, g);
    agg_kernel<<<agg_grid, 256, 0, stream>>>(g, dinv, offsets, csr, b2, out);
    // ---- layer 3 ----
    gemm_norm_kernel<<<gemm_grid, 256, 0, stream>>>(out, W3, dinv, g);
    agg_kernel<<<agg_grid, 256, 0, stream>>>(g, dinv, offsets, csr, b3, out);
}

// Round 4
// 544.641 us; speedup vs baseline: 15.4612x; 1.2105x over previous
//
#include <hip/hip_runtime.h>
#include <hip/hip_fp16.h>
#include <math.h>

#define NN 100000
#define DD 128
#define SCAN_CHUNK 2048

// ---------------- degree histogram (int) ----------------
__global__ void hist_kernel(const int* __restrict__ dst, int E, int* __restrict__ deg) {
    int i = blockIdx.x * blockDim.x + threadIdx.x;
    if (i < E) atomicAdd(&deg[dst[i]], 1);
}

// ---------------- dinv = rsqrt(indeg + 1) ----------------
__global__ void dinv_kernel(const int* __restrict__ deg, float* __restrict__ dinv, int n) {
    int i = blockIdx.x * blockDim.x + threadIdx.x;
    if (i < n) dinv[i] = rsqrtf((float)deg[i] + 1.0f);
}

// ---------------- scan part 1: per-chunk sums ----------------
__global__ __launch_bounds__(256) void scan1_kernel(const int* __restrict__ deg,
                                                    int* __restrict__ chunkSum, int n) {
    __shared__ int lds[256];
    int tid = threadIdx.x;
    int base = blockIdx.x * SCAN_CHUNK + tid * 8;
    int s = 0;
    #pragma unroll
    for (int j = 0; j < 8; ++j) {
        int idx = base + j;
        if (idx < n) s += deg[idx];
    }
    lds[tid] = s;
    __syncthreads();
    for (int d = 128; d > 0; d >>= 1) {
        if (tid < d) lds[tid] += lds[tid + d];
        __syncthreads();
    }
    if (tid == 0) chunkSum[blockIdx.x] = lds[0];
}

// ---------------- scan part 2: scan chunk sums (1 block) ----------------
__global__ void scan2_kernel(int* __restrict__ chunkSum, int* __restrict__ chunkOff,
                             int nb, int* __restrict__ offsets) {
    __shared__ int lds[512];
    int tid = threadIdx.x;
    if (tid < nb) lds[tid] = chunkSum[tid];
    __syncthreads();
    if (tid == 0) {
        int run = 0;
        for (int i = 0; i < nb; ++i) {
            int v = lds[i];
            lds[i] = run;
            run += v;
        }
        offsets[NN] = run;
    }
    __syncthreads();
    if (tid < nb) chunkOff[tid] = lds[tid];
}

// ---------------- scan part 3: per-chunk exclusive scan ----------------
__global__ __launch_bounds__(256) void scan3_kernel(const int* __restrict__ deg,
                                                    const int* __restrict__ chunkOff,
                                                    int* __restrict__ offsets, int n) {
    __shared__ int lds[256];
    int tid = threadIdx.x;
    int base = blockIdx.x * SCAN_CHUNK + tid * 8;
    int v[8];
    int tsum = 0;
    #pragma unroll
    for (int j = 0; j < 8; ++j) {
        int idx = base + j;
        v[j] = (idx < n) ? deg[idx] : 0;
        tsum += v[j];
    }
    lds[tid] = tsum;
    __syncthreads();
    for (int d = 1; d < 256; d <<= 1) {
        int t = (tid >= d) ? lds[tid - d] : 0;
        __syncthreads();
        lds[tid] += t;
        __syncthreads();
    }
    int excl = lds[tid] - tsum;
    int off0 = chunkOff[blockIdx.x] + excl;
    int run = 0;
    #pragma unroll
    for (int j = 0; j < 8; ++j) {
        int idx = base + j;
        if (idx < n) offsets[idx] = off0 + run;
        run += v[j];
    }
}

// ---------------- CSR fill (destroys deg) ----------------
__global__ void fill_kernel(const int* __restrict__ src, const int* __restrict__ dst, int E,
                            const int* __restrict__ offsets, int* __restrict__ deg,
                            int* __restrict__ csr) {
    int e = blockIdx.x * blockDim.x + threadIdx.x;
    if (e >= E) return;
    int d = dst[e];
    int old = atomicSub(&deg[d], 1);
    csr[offsets[d + 1] - old] = src[e];
}

// ---------------- GEMM + src-norm fuse: g = fp16((X @ W) * dinv[row]) ----------------
// 128-row tile, 256 threads; thread = 4 rows x 16 cols.
// Only W lives in LDS (64 KB -> 2 blocks/CU). X streams global->reg with
// one-chunk-deep prefetch; 8 lanes per rp share each X float4 (coalesced).
__global__ __launch_bounds__(256, 2) void gemm_norm_kernel(
    const float* __restrict__ X, const float* __restrict__ W,
    const float* __restrict__ dinv, __half* __restrict__ G)
{
    __shared__ float ws[128 * 128];     // 64 KB

    const int tid  = threadIdx.x;
    const int base = blockIdx.x * 128;

    // stage W (16384 floats = 4096 float4)
    {
        const float4* W4 = (const float4*)W;
        float4* S4 = (float4*)ws;
        #pragma unroll
        for (int it = 0; it < 16; ++it) S4[tid + it * 256] = W4[tid + it * 256];
    }
    __syncthreads();

    const int cg = tid & 7;        // cols cg*4 + s*32
    const int rp = tid >> 3;       // 0..31
    const int r0 = rp * 4;

    const float4* xp[4];
    int rows[4];
    #pragma unroll
    for (int r = 0; r < 4; ++r) {
        int row = base + r0 + r;
        rows[r] = row;
        int rc = (row < NN) ? row : (NN - 1);   // clamp: safe read, store guarded
        xp[r] = (const float4*)&X[(size_t)rc * DD];
    }

    float acc[4][4][4];            // [row][s][col]
    #pragma unroll
    for (int r = 0; r < 4; ++r)
        #pragma unroll
        for (int s = 0; s < 4; ++s)
            #pragma unroll
            for (int c = 0; c < 4; ++c) acc[r][s][c] = 0.f;

    float4 cur[4], nxt[4];
    #pragma unroll
    for (int r = 0; r < 4; ++r) cur[r] = xp[r][0];

    for (int kc = 0; kc < 32; ++kc) {
        if (kc + 1 < 32) {
            #pragma unroll
            for (int r = 0; r < 4; ++r) nxt[r] = xp[r][kc + 1];
        }
        const float* wb = &ws[kc * 4 * 128];
        #pragma unroll
        for (int kk = 0; kk < 4; ++kk) {
            float xk0 = ((const float*)&cur[0])[kk];
            float xk1 = ((const float*)&cur[1])[kk];
            float xk2 = ((const float*)&cur[2])[kk];
            float xk3 = ((const float*)&cur[3])[kk];
            #pragma unroll
            for (int s = 0; s < 4; ++s) {
                const float4 wv = *(const float4*)&wb[kk * 128 + cg * 4 + s * 32];
                acc[0][s][0] += xk0 * wv.x; acc[0][s][1] += xk0 * wv.y;
                acc[0][s][2] += xk0 * wv.z; acc[0][s][3] += xk0 * wv.w;
                acc[1][s][0] += xk1 * wv.x; acc[1][s][1] += xk1 * wv.y;
                acc[1][s][2] += xk1 * wv.z; acc[1][s][3] += xk1 * wv.w;
                acc[2][s][0] += xk2 * wv.x; acc[2][s][1] += xk2 * wv.y;
                acc[2][s][2] += xk2 * wv.z; acc[2][s][3] += xk2 * wv.w;
                acc[3][s][0] += xk3 * wv.x; acc[3][s][1] += xk3 * wv.y;
                acc[3][s][2] += xk3 * wv.z; acc[3][s][3] += xk3 * wv.w;
            }
        }
        #pragma unroll
        for (int r = 0; r < 4; ++r) cur[r] = nxt[r];
    }

    #pragma unroll
    for (int r = 0; r < 4; ++r) {
        if (rows[r] < NN) {
            float di = dinv[rows[r]];
            #pragma unroll
            for (int s = 0; s < 4; ++s) {
                __half2 h01 = __floats2half2_rn(acc[r][s][0] * di, acc[r][s][1] * di);
                __half2 h23 = __floats2half2_rn(acc[r][s][2] * di, acc[r][s][3] * di);
                __half2* gp = (__half2*)&G[rows[r] * DD + cg * 4 + s * 32];
                gp[0] = h01;
                gp[1] = h23;
            }
        }
    }
}

// ---------------- gather-aggregate + bias + relu ----------------
// one wave per dst node; lane holds half2 slice (2 cols) of the 128-wide row
__global__ __launch_bounds__(256) void agg_kernel(
    const __half* __restrict__ g, const float* __restrict__ dinv,
    const int* __restrict__ off, const int* __restrict__ csr,
    const float* __restrict__ bias, float* __restrict__ out)
{
    int node = (blockIdx.x * 256 + threadIdx.x) >> 6;
    if (node >= NN) return;
    int lane = threadIdx.x & 63;
    const __half2* __restrict__ g2 = (const __half2*)g;

    float2 acc = __half22float2(g2[node * 64 + lane]);   // self-loop message
    int e = off[node], end = off[node + 1];

    for (; e + 4 <= end; e += 4) {
        int s0 = csr[e], s1 = csr[e + 1], s2 = csr[e + 2], s3 = csr[e + 3];
        float2 v0 = __half22float2(g2[s0 * 64 + lane]);
        float2 v1 = __half22float2(g2[s1 * 64 + lane]);
        float2 v2 = __half22float2(g2[s2 * 64 + lane]);
        float2 v3 = __half22float2(g2[s3 * 64 + lane]);
        acc.x += (v0.x + v1.x) + (v2.x + v3.x);
        acc.y += (v0.y + v1.y) + (v2.y + v3.y);
    }
    for (; e < end; ++e) {
        float2 v = __half22float2(g2[csr[e] * 64 + lane]);
        acc.x += v.x; acc.y += v.y;
    }

    float di = dinv[node];
    float2 bb = ((const float2*)bias)[lane];
    float2 o;
    o.x = fmaxf(fmaf(acc.x, di, bb.x), 0.f);
    o.y = fmaxf(fmaf(acc.y, di, bb.y), 0.f);
    ((float2*)out)[node * 64 + lane] = o;
}

extern "C" void kernel_launch(void* const* d_in, const int* in_sizes, int n_in,
                              void* d_out, int out_size, void* d_ws, size_t ws_size,
                              hipStream_t stream)
{
    const float* x  = (const float*)d_in[0];
    const float* W1 = (const float*)d_in[1];
    const float* b1 = (const float*)d_in[2];
    const float* W2 = (const float*)d_in[3];
    const float* b2 = (const float*)d_in[4];
    const float* W3 = (const float*)d_in[5];
    const float* b3 = (const float*)d_in[6];
    const int*   ei = (const int*)d_in[7];

    const int E = in_sizes[7] / 2;          // 1,600,000
    const int* src = ei;
    const int* dst = ei + E;

    float* out = (float*)d_out;

    // ---- workspace layout ----
    char* wsb = (char*)d_ws;
    size_t p = 0;
    int* deg      = (int*)(wsb + p); p += ((size_t)NN * 4 + 1023) & ~1023ull;
    int* offsets  = (int*)(wsb + p); p += ((size_t)(NN + 1) * 4 + 1023) & ~1023ull;
    int* chunkSum = (int*)(wsb + p); p += 4096;
    int* chunkOff = (int*)(wsb + p); p += 4096;
    int* csr      = (int*)(wsb + p); p += ((size_t)E * 4 + 1023) & ~1023ull;
    float* dinv   = (float*)(wsb + p); p += ((size_t)NN * 4 + 1023) & ~1023ull;
    __half* g     = (__half*)(wsb + p); p += (size_t)NN * DD * 2;

    const int NB = (NN + SCAN_CHUNK - 1) / SCAN_CHUNK;   // 49

    // ---- CSR build + dinv ----
    hipMemsetAsync(deg, 0, (size_t)NN * 4, stream);
    hist_kernel<<<(E + 255) / 256, 256, 0, stream>>>(dst, E, deg);
    dinv_kernel<<<(NN + 255) / 256, 256, 0, stream>>>(deg, dinv, NN);
    scan1_kernel<<<NB, 256, 0, stream>>>(deg, chunkSum, NN);
    scan2_kernel<<<1, 512, 0, stream>>>(chunkSum, chunkOff, NB, offsets);
    scan3_kernel<<<NB, 256, 0, stream>>>(deg, chunkOff, offsets, NN);
    fill_kernel<<<(E + 255) / 256, 256, 0, stream>>>(src, dst, E, offsets, deg, csr);

    const int gemm_grid = (NN + 127) / 128;               // 782
    const int agg_grid  = ((size_t)NN * 64 + 255) / 256;  // 25000

    // ---- layer 1 ----
    gemm_norm_kernel<<<gemm_grid, 256, 0, stream>>>(x, W1, dinv, g);
    agg_kernel<<<agg_grid, 256, 0, stream>>>(g, dinv, offsets, csr, b1, out);
    // ---- layer 2 ----
    gemm_norm_kernel<<<gemm_grid, 256, 0, stream>>>(out, W2, dinv, g);
    agg_kernel<<<agg_grid, 256, 0, stream>>>(g, dinv, offsets, csr, b2, out);
    // ---- layer 3 ----
    gemm_norm_kernel<<<gemm_grid, 256, 0, stream>>>(out, W3, dinv, g);
    agg_kernel<<<agg_grid, 256, 0, stream>>>(g, dinv, offsets, csr, b3, out);
}

// Round 5
// 479.485 us; speedup vs baseline: 17.5622x; 1.1359x over previous
//
#include <hip/hip_runtime.h>
#include <hip/hip_fp16.h>
#include <math.h>

#define NN 100000
#define DD 128
#define SCAN_CHUNK 2048

// ---------------- degree histogram + per-edge rank ----------------
// rank[e] = position of edge e within its dst bucket (arrival order)
__global__ __launch_bounds__(256) void hist_rank_kernel(const int* __restrict__ dst, int E,
                                                        int* __restrict__ deg,
                                                        int* __restrict__ rank) {
    int i = blockIdx.x * 256 + threadIdx.x;
    int e = i * 4;
    if (e + 3 < E) {
        int4 d4 = ((const int4*)dst)[i];
        int4 r4;
        r4.x = atomicAdd(&deg[d4.x], 1);
        r4.y = atomicAdd(&deg[d4.y], 1);
        r4.z = atomicAdd(&deg[d4.z], 1);
        r4.w = atomicAdd(&deg[d4.w], 1);
        ((int4*)rank)[i] = r4;
    } else {
        for (; e < E; ++e) rank[e] = atomicAdd(&deg[dst[e]], 1);
    }
}

// ---------------- dinv = rsqrt(indeg + 1) ----------------
__global__ void dinv_kernel(const int* __restrict__ deg, float* __restrict__ dinv, int n) {
    int i = blockIdx.x * blockDim.x + threadIdx.x;
    if (i < n) dinv[i] = rsqrtf((float)deg[i] + 1.0f);
}

// ---------------- scan part 1: per-chunk sums ----------------
__global__ __launch_bounds__(256) void scan1_kernel(const int* __restrict__ deg,
                                                    int* __restrict__ chunkSum, int n) {
    __shared__ int lds[256];
    int tid = threadIdx.x;
    int base = blockIdx.x * SCAN_CHUNK + tid * 8;
    int s = 0;
    #pragma unroll
    for (int j = 0; j < 8; ++j) {
        int idx = base + j;
        if (idx < n) s += deg[idx];
    }
    lds[tid] = s;
    __syncthreads();
    for (int d = 128; d > 0; d >>= 1) {
        if (tid < d) lds[tid] += lds[tid + d];
        __syncthreads();
    }
    if (tid == 0) chunkSum[blockIdx.x] = lds[0];
}

// ---------------- scan part 2: scan chunk sums (1 block) ----------------
__global__ void scan2_kernel(int* __restrict__ chunkSum, int* __restrict__ chunkOff,
                             int nb, int* __restrict__ offsets) {
    __shared__ int lds[512];
    int tid = threadIdx.x;
    if (tid < nb) lds[tid] = chunkSum[tid];
    __syncthreads();
    if (tid == 0) {
        int run = 0;
        for (int i = 0; i < nb; ++i) {
            int v = lds[i];
            lds[i] = run;
            run += v;
        }
        offsets[NN] = run;
    }
    __syncthreads();
    if (tid < nb) chunkOff[tid] = lds[tid];
}

// ---------------- scan part 3: per-chunk exclusive scan ----------------
__global__ __launch_bounds__(256) void scan3_kernel(const int* __restrict__ deg,
                                                    const int* __restrict__ chunkOff,
                                                    int* __restrict__ offsets, int n) {
    __shared__ int lds[256];
    int tid = threadIdx.x;
    int base = blockIdx.x * SCAN_CHUNK + tid * 8;
    int v[8];
    int tsum = 0;
    #pragma unroll
    for (int j = 0; j < 8; ++j) {
        int idx = base + j;
        v[j] = (idx < n) ? deg[idx] : 0;
        tsum += v[j];
    }
    lds[tid] = tsum;
    __syncthreads();
    for (int d = 1; d < 256; d <<= 1) {
        int t = (tid >= d) ? lds[tid - d] : 0;
        __syncthreads();
        lds[tid] += t;
        __syncthreads();
    }
    int excl = lds[tid] - tsum;
    int off0 = chunkOff[blockIdx.x] + excl;
    int run = 0;
    #pragma unroll
    for (int j = 0; j < 8; ++j) {
        int idx = base + j;
        if (idx < n) offsets[idx] = off0 + run;
        run += v[j];
    }
}

// ---------------- CSR fill (atomic-free) ----------------
__global__ __launch_bounds__(256) void fill_kernel(const int* __restrict__ src,
                                                   const int* __restrict__ dst,
                                                   const int* __restrict__ rank, int E,
                                                   const int* __restrict__ offsets,
                                                   int* __restrict__ csr) {
    int i = blockIdx.x * 256 + threadIdx.x;
    int e = i * 4;
    if (e + 3 < E) {
        int4 d4 = ((const int4*)dst)[i];
        int4 s4 = ((const int4*)src)[i];
        int4 r4 = ((const int4*)rank)[i];
        int o0 = offsets[d4.x];
        int o1 = offsets[d4.y];
        int o2 = offsets[d4.z];
        int o3 = offsets[d4.w];
        csr[o0 + r4.x] = s4.x;
        csr[o1 + r4.y] = s4.y;
        csr[o2 + r4.z] = s4.z;
        csr[o3 + r4.w] = s4.w;
    } else {
        for (; e < E; ++e) csr[offsets[dst[e]] + rank[e]] = src[e];
    }
}

// ---------------- GEMM + src-norm fuse: g = fp16((X @ W) * dinv[row]) ----------------
__global__ __launch_bounds__(256, 2) void gemm_norm_kernel(
    const float* __restrict__ X, const float* __restrict__ W,
    const float* __restrict__ dinv, __half* __restrict__ G)
{
    __shared__ float ws[128 * 128];     // 64 KB

    const int tid  = threadIdx.x;
    const int base = blockIdx.x * 128;

    {
        const float4* W4 = (const float4*)W;
        float4* S4 = (float4*)ws;
        #pragma unroll
        for (int it = 0; it < 16; ++it) S4[tid + it * 256] = W4[tid + it * 256];
    }
    __syncthreads();

    const int cg = tid & 7;        // cols cg*4 + s*32
    const int rp = tid >> 3;       // 0..31
    const int r0 = rp * 4;

    const float4* xp[4];
    int rows[4];
    #pragma unroll
    for (int r = 0; r < 4; ++r) {
        int row = base + r0 + r;
        rows[r] = row;
        int rc = (row < NN) ? row : (NN - 1);
        xp[r] = (const float4*)&X[(size_t)rc * DD];
    }

    float acc[4][4][4];
    #pragma unroll
    for (int r = 0; r < 4; ++r)
        #pragma unroll
        for (int s = 0; s < 4; ++s)
            #pragma unroll
            for (int c = 0; c < 4; ++c) acc[r][s][c] = 0.f;

    float4 cur[4], nxt[4];
    #pragma unroll
    for (int r = 0; r < 4; ++r) cur[r] = xp[r][0];

    for (int kc = 0; kc < 32; ++kc) {
        if (kc + 1 < 32) {
            #pragma unroll
            for (int r = 0; r < 4; ++r) nxt[r] = xp[r][kc + 1];
        }
        const float* wb = &ws[kc * 4 * 128];
        #pragma unroll
        for (int kk = 0; kk < 4; ++kk) {
            float xk0 = ((const float*)&cur[0])[kk];
            float xk1 = ((const float*)&cur[1])[kk];
            float xk2 = ((const float*)&cur[2])[kk];
            float xk3 = ((const float*)&cur[3])[kk];
            #pragma unroll
            for (int s = 0; s < 4; ++s) {
                const float4 wv = *(const float4*)&wb[kk * 128 + cg * 4 + s * 32];
                acc[0][s][0] += xk0 * wv.x; acc[0][s][1] += xk0 * wv.y;
                acc[0][s][2] += xk0 * wv.z; acc[0][s][3] += xk0 * wv.w;
                acc[1][s][0] += xk1 * wv.x; acc[1][s][1] += xk1 * wv.y;
                acc[1][s][2] += xk1 * wv.z; acc[1][s][3] += xk1 * wv.w;
                acc[2][s][0] += xk2 * wv.x; acc[2][s][1] += xk2 * wv.y;
                acc[2][s][2] += xk2 * wv.z; acc[2][s][3] += xk2 * wv.w;
                acc[3][s][0] += xk3 * wv.x; acc[3][s][1] += xk3 * wv.y;
                acc[3][s][2] += xk3 * wv.z; acc[3][s][3] += xk3 * wv.w;
            }
        }
        #pragma unroll
        for (int r = 0; r < 4; ++r) cur[r] = nxt[r];
    }

    #pragma unroll
    for (int r = 0; r < 4; ++r) {
        if (rows[r] < NN) {
            float di = dinv[rows[r]];
            #pragma unroll
            for (int s = 0; s < 4; ++s) {
                __half2 h01 = __floats2half2_rn(acc[r][s][0] * di, acc[r][s][1] * di);
                __half2 h23 = __floats2half2_rn(acc[r][s][2] * di, acc[r][s][3] * di);
                __half2* gp = (__half2*)&G[rows[r] * DD + cg * 4 + s * 32];
                gp[0] = h01;
                gp[1] = h23;
            }
        }
    }
}

// ---------------- gather-aggregate + bias + relu ----------------
__global__ __launch_bounds__(256) void agg_kernel(
    const __half* __restrict__ g, const float* __restrict__ dinv,
    const int* __restrict__ off, const int* __restrict__ csr,
    const float* __restrict__ bias, float* __restrict__ out)
{
    int node = (blockIdx.x * 256 + threadIdx.x) >> 6;
    if (node >= NN) return;
    int lane = threadIdx.x & 63;
    const __half2* __restrict__ g2 = (const __half2*)g;

    float2 acc = __half22float2(g2[node * 64 + lane]);   // self-loop message
    int e = off[node], end = off[node + 1];

    for (; e + 4 <= end; e += 4) {
        int s0 = csr[e], s1 = csr[e + 1], s2 = csr[e + 2], s3 = csr[e + 3];
        float2 v0 = __half22float2(g2[s0 * 64 + lane]);
        float2 v1 = __half22float2(g2[s1 * 64 + lane]);
        float2 v2 = __half22float2(g2[s2 * 64 + lane]);
        float2 v3 = __half22float2(g2[s3 * 64 + lane]);
        acc.x += (v0.x + v1.x) + (v2.x + v3.x);
        acc.y += (v0.y + v1.y) + (v2.y + v3.y);
    }
    for (; e < end; ++e) {
        float2 v = __half22float2(g2[csr[e] * 64 + lane]);
        acc.x += v.x; acc.y += v.y;
    }

    float di = dinv[node];
    float2 bb = ((const float2*)bias)[lane];
    float2 o;
    o.x = fmaxf(fmaf(acc.x, di, bb.x), 0.f);
    o.y = fmaxf(fmaf(acc.y, di, bb.y), 0.f);
    ((float2*)out)[node * 64 + lane] = o;
}

extern "C" void kernel_launch(void* const* d_in, const int* in_sizes, int n_in,
                              void* d_out, int out_size, void* d_ws, size_t ws_size,
                              hipStream_t stream)
{
    const float* x  = (const float*)d_in[0];
    const float* W1 = (const float*)d_in[1];
    const float* b1 = (const float*)d_in[2];
    const float* W2 = (const float*)d_in[3];
    const float* b2 = (const float*)d_in[4];
    const float* W3 = (const float*)d_in[5];
    const float* b3 = (const float*)d_in[6];
    const int*   ei = (const int*)d_in[7];

    const int E = in_sizes[7] / 2;          // 1,600,000
    const int* src = ei;
    const int* dst = ei + E;

    float* out = (float*)d_out;

    // ---- workspace layout ----
    char* wsb = (char*)d_ws;
    size_t p = 0;
    int* deg      = (int*)(wsb + p); p += ((size_t)NN * 4 + 1023) & ~1023ull;
    int* offsets  = (int*)(wsb + p); p += ((size_t)(NN + 1) * 4 + 1023) & ~1023ull;
    int* chunkSum = (int*)(wsb + p); p += 4096;
    int* chunkOff = (int*)(wsb + p); p += 4096;
    int* csr      = (int*)(wsb + p); p += ((size_t)E * 4 + 1023) & ~1023ull;
    int* rank     = (int*)(wsb + p); p += ((size_t)E * 4 + 1023) & ~1023ull;
    float* dinv   = (float*)(wsb + p); p += ((size_t)NN * 4 + 1023) & ~1023ull;
    __half* g     = (__half*)(wsb + p); p += (size_t)NN * DD * 2;

    const int NB = (NN + SCAN_CHUNK - 1) / SCAN_CHUNK;   // 49

    // ---- CSR build + dinv ----
    hipMemsetAsync(deg, 0, (size_t)NN * 4, stream);
    hist_rank_kernel<<<(E / 4 + 256) / 256 + 1, 256, 0, stream>>>(dst, E, deg, rank);
    dinv_kernel<<<(NN + 255) / 256, 256, 0, stream>>>(deg, dinv, NN);
    scan1_kernel<<<NB, 256, 0, stream>>>(deg, chunkSum, NN);
    scan2_kernel<<<1, 512, 0, stream>>>(chunkSum, chunkOff, NB, offsets);
    scan3_kernel<<<NB, 256, 0, stream>>>(deg, chunkOff, offsets, NN);
    fill_kernel<<<(E / 4 + 256) / 256 + 1, 256, 0, stream>>>(src, dst, rank, E, offsets, csr);

    const int gemm_grid = (NN + 127) / 128;               // 782
    const int agg_grid  = ((size_t)NN * 64 + 255) / 256;  // 25000

    // ---- layer 1 ----
    gemm_norm_kernel<<<gemm_grid, 256, 0, stream>>>(x, W1, dinv, g);
    agg_kernel<<<agg_grid, 256, 0, stream>>>(g, dinv, offsets, csr, b1, out);
    // ---- layer 2 ----
    gemm_norm_kernel<<<gemm_grid, 256, 0, stream>>>(out, W2, dinv, g);
    agg_kernel<<<agg_grid, 256, 0, stream>>>(g, dinv, offsets, csr, b2, out);
    // ---- layer 3 ----
    gemm_norm_kernel<<<gemm_grid, 256, 0, stream>>>(out, W3, dinv, g);
    agg_kernel<<<agg_grid, 256, 0, stream>>>(g, dinv, offsets, csr, b3, out);
}

// Round 6
// 479.125 us; speedup vs baseline: 17.5754x; 1.0008x over previous
//
#include <hip/hip_runtime.h>
#include <hip/hip_fp16.h>
#include <math.h>

#define NN 100000
#define DD 128
#define SCAN_CHUNK 2048

// ---------------- degree histogram + per-edge rank ----------------
__global__ __launch_bounds__(256) void hist_rank_kernel(const int* __restrict__ dst, int E,
                                                        int* __restrict__ deg,
                                                        int* __restrict__ rank) {
    int i = blockIdx.x * 256 + threadIdx.x;
    int e = i * 4;
    if (e + 3 < E) {
        int4 d4 = ((const int4*)dst)[i];
        int4 r4;
        r4.x = atomicAdd(&deg[d4.x], 1);
        r4.y = atomicAdd(&deg[d4.y], 1);
        r4.z = atomicAdd(&deg[d4.z], 1);
        r4.w = atomicAdd(&deg[d4.w], 1);
        ((int4*)rank)[i] = r4;
    } else {
        for (; e < E; ++e) rank[e] = atomicAdd(&deg[dst[e]], 1);
    }
}

// ---------------- scan part 1: per-chunk sums (+ fused dinv) ----------------
__global__ __launch_bounds__(256) void scan1_kernel(const int* __restrict__ deg,
                                                    int* __restrict__ chunkSum,
                                                    float* __restrict__ dinv, int n) {
    __shared__ int lds[256];
    int tid = threadIdx.x;
    int base = blockIdx.x * SCAN_CHUNK + tid * 8;
    int s = 0;
    #pragma unroll
    for (int j = 0; j < 8; ++j) {
        int idx = base + j;
        if (idx < n) {
            int d = deg[idx];
            s += d;
            dinv[idx] = rsqrtf((float)d + 1.0f);
        }
    }
    lds[tid] = s;
    __syncthreads();
    for (int d = 128; d > 0; d >>= 1) {
        if (tid < d) lds[tid] += lds[tid + d];
        __syncthreads();
    }
    if (tid == 0) chunkSum[blockIdx.x] = lds[0];
}

// ---------------- scan part 2: scan chunk sums (1 block) ----------------
__global__ void scan2_kernel(int* __restrict__ chunkSum, int* __restrict__ chunkOff,
                             int nb, int* __restrict__ offsets) {
    __shared__ int lds[512];
    int tid = threadIdx.x;
    if (tid < nb) lds[tid] = chunkSum[tid];
    __syncthreads();
    if (tid == 0) {
        int run = 0;
        for (int i = 0; i < nb; ++i) {
            int v = lds[i];
            lds[i] = run;
            run += v;
        }
        offsets[NN] = run;
    }
    __syncthreads();
    if (tid < nb) chunkOff[tid] = lds[tid];
}

// ---------------- scan part 3: per-chunk exclusive scan ----------------
__global__ __launch_bounds__(256) void scan3_kernel(const int* __restrict__ deg,
                                                    const int* __restrict__ chunkOff,
                                                    int* __restrict__ offsets, int n) {
    __shared__ int lds[256];
    int tid = threadIdx.x;
    int base = blockIdx.x * SCAN_CHUNK + tid * 8;
    int v[8];
    int tsum = 0;
    #pragma unroll
    for (int j = 0; j < 8; ++j) {
        int idx = base + j;
        v[j] = (idx < n) ? deg[idx] : 0;
        tsum += v[j];
    }
    lds[tid] = tsum;
    __syncthreads();
    for (int d = 1; d < 256; d <<= 1) {
        int t = (tid >= d) ? lds[tid - d] : 0;
        __syncthreads();
        lds[tid] += t;
        __syncthreads();
    }
    int excl = lds[tid] - tsum;
    int off0 = chunkOff[blockIdx.x] + excl;
    int run = 0;
    #pragma unroll
    for (int j = 0; j < 8; ++j) {
        int idx = base + j;
        if (idx < n) offsets[idx] = off0 + run;
        run += v[j];
    }
}

// ---------------- CSR fill (atomic-free) ----------------
__global__ __launch_bounds__(256) void fill_kernel(const int* __restrict__ src,
                                                   const int* __restrict__ dst,
                                                   const int* __restrict__ rank, int E,
                                                   const int* __restrict__ offsets,
                                                   int* __restrict__ csr) {
    int i = blockIdx.x * 256 + threadIdx.x;
    int e = i * 4;
    if (e + 3 < E) {
        int4 d4 = ((const int4*)dst)[i];
        int4 s4 = ((const int4*)src)[i];
        int4 r4 = ((const int4*)rank)[i];
        int o0 = offsets[d4.x];
        int o1 = offsets[d4.y];
        int o2 = offsets[d4.z];
        int o3 = offsets[d4.w];
        csr[o0 + r4.x] = s4.x;
        csr[o1 + r4.y] = s4.y;
        csr[o2 + r4.z] = s4.z;
        csr[o3 + r4.w] = s4.w;
    } else {
        for (; e < E; ++e) csr[offsets[dst[e]] + rank[e]] = src[e];
    }
}

// ---------------- GEMM + src-norm fuse: g = fp16((X @ W) * dinv[row]) ----------------
__global__ __launch_bounds__(256, 2) void gemm_norm_kernel(
    const float* __restrict__ X, const float* __restrict__ W,
    const float* __restrict__ dinv, __half* __restrict__ G)
{
    __shared__ float ws[128 * 128];     // 64 KB

    const int tid  = threadIdx.x;
    const int base = blockIdx.x * 128;

    {
        const float4* W4 = (const float4*)W;
        float4* S4 = (float4*)ws;
        #pragma unroll
        for (int it = 0; it < 16; ++it) S4[tid + it * 256] = W4[tid + it * 256];
    }
    __syncthreads();

    const int cg = tid & 7;        // cols cg*4 + s*32
    const int rp = tid >> 3;       // 0..31
    const int r0 = rp * 4;

    const float4* xp[4];
    int rows[4];
    #pragma unroll
    for (int r = 0; r < 4; ++r) {
        int row = base + r0 + r;
        rows[r] = row;
        int rc = (row < NN) ? row : (NN - 1);
        xp[r] = (const float4*)&X[(size_t)rc * DD];
    }

    float acc[4][4][4];
    #pragma unroll
    for (int r = 0; r < 4; ++r)
        #pragma unroll
        for (int s = 0; s < 4; ++s)
            #pragma unroll
            for (int c = 0; c < 4; ++c) acc[r][s][c] = 0.f;

    float4 cur[4], nxt[4];
    #pragma unroll
    for (int r = 0; r < 4; ++r) cur[r] = xp[r][0];

    for (int kc = 0; kc < 32; ++kc) {
        if (kc + 1 < 32) {
            #pragma unroll
            for (int r = 0; r < 4; ++r) nxt[r] = xp[r][kc + 1];
        }
        const float* wb = &ws[kc * 4 * 128];
        #pragma unroll
        for (int kk = 0; kk < 4; ++kk) {
            float xk0 = ((const float*)&cur[0])[kk];
            float xk1 = ((const float*)&cur[1])[kk];
            float xk2 = ((const float*)&cur[2])[kk];
            float xk3 = ((const float*)&cur[3])[kk];
            #pragma unroll
            for (int s = 0; s < 4; ++s) {
                const float4 wv = *(const float4*)&wb[kk * 128 + cg * 4 + s * 32];
                acc[0][s][0] += xk0 * wv.x; acc[0][s][1] += xk0 * wv.y;
                acc[0][s][2] += xk0 * wv.z; acc[0][s][3] += xk0 * wv.w;
                acc[1][s][0] += xk1 * wv.x; acc[1][s][1] += xk1 * wv.y;
                acc[1][s][2] += xk1 * wv.z; acc[1][s][3] += xk1 * wv.w;
                acc[2][s][0] += xk2 * wv.x; acc[2][s][1] += xk2 * wv.y;
                acc[2][s][2] += xk2 * wv.z; acc[2][s][3] += xk2 * wv.w;
                acc[3][s][0] += xk3 * wv.x; acc[3][s][1] += xk3 * wv.y;
                acc[3][s][2] += xk3 * wv.z; acc[3][s][3] += xk3 * wv.w;
            }
        }
        #pragma unroll
        for (int r = 0; r < 4; ++r) cur[r] = nxt[r];
    }

    #pragma unroll
    for (int r = 0; r < 4; ++r) {
        if (rows[r] < NN) {
            float di = dinv[rows[r]];
            #pragma unroll
            for (int s = 0; s < 4; ++s) {
                __half2 h01 = __floats2half2_rn(acc[r][s][0] * di, acc[r][s][1] * di);
                __half2 h23 = __floats2half2_rn(acc[r][s][2] * di, acc[r][s][3] * di);
                __half2* gp = (__half2*)&G[rows[r] * DD + cg * 4 + s * 32];
                gp[0] = h01;
                gp[1] = h23;
            }
        }
    }
}

// ---------------- gather-aggregate + bias + relu ----------------
// one wave per dst node; lane holds half2 slice (2 cols) of the 128-wide row.
// 8-wide software pipeline: prefetch next 8 indices while 8 gathers in flight.
__global__ __launch_bounds__(256) void agg_kernel(
    const __half* __restrict__ g, const float* __restrict__ dinv,
    const int* __restrict__ off, const int* __restrict__ csr,
    const float* __restrict__ bias, float* __restrict__ out)
{
    int node = (blockIdx.x * 256 + threadIdx.x) >> 6;
    if (node >= NN) return;
    int lane = threadIdx.x & 63;
    const __half2* __restrict__ g2 = (const __half2*)g;

    float2 acc0 = __half22float2(g2[node * 64 + lane]);   // self-loop message
    float2 acc1 = make_float2(0.f, 0.f);

    int e = off[node], end = off[node + 1];
    int cnt = end - e;
    int e8end = e + (cnt & ~7);

    if (e < e8end) {
        int idx[8];
        #pragma unroll
        for (int j = 0; j < 8; ++j) idx[j] = csr[e + j];
        e += 8;
        for (; e < e8end; e += 8) {
            int nidx[8];
            #pragma unroll
            for (int j = 0; j < 8; ++j) nidx[j] = csr[e + j];
            #pragma unroll
            for (int j = 0; j < 8; j += 2) {
                float2 v0 = __half22float2(g2[idx[j] * 64 + lane]);
                float2 v1 = __half22float2(g2[idx[j + 1] * 64 + lane]);
                acc0.x += v0.x; acc0.y += v0.y;
                acc1.x += v1.x; acc1.y += v1.y;
            }
            #pragma unroll
            for (int j = 0; j < 8; ++j) idx[j] = nidx[j];
        }
        #pragma unroll
        for (int j = 0; j < 8; j += 2) {
            float2 v0 = __half22float2(g2[idx[j] * 64 + lane]);
            float2 v1 = __half22float2(g2[idx[j + 1] * 64 + lane]);
            acc0.x += v0.x; acc0.y += v0.y;
            acc1.x += v1.x; acc1.y += v1.y;
        }
    }
    for (; e < end; ++e) {
        float2 v = __half22float2(g2[csr[e] * 64 + lane]);
        acc0.x += v.x; acc0.y += v.y;
    }

    float di = dinv[node];
    float2 bb = ((const float2*)bias)[lane];
    float2 o;
    o.x = fmaxf(fmaf(acc0.x + acc1.x, di, bb.x), 0.f);
    o.y = fmaxf(fmaf(acc0.y + acc1.y, di, bb.y), 0.f);
    ((float2*)out)[node * 64 + lane] = o;
}

extern "C" void kernel_launch(void* const* d_in, const int* in_sizes, int n_in,
                              void* d_out, int out_size, void* d_ws, size_t ws_size,
                              hipStream_t stream)
{
    const float* x  = (const float*)d_in[0];
    const float* W1 = (const float*)d_in[1];
    const float* b1 = (const float*)d_in[2];
    const float* W2 = (const float*)d_in[3];
    const float* b2 = (const float*)d_in[4];
    const float* W3 = (const float*)d_in[5];
    const float* b3 = (const float*)d_in[6];
    const int*   ei = (const int*)d_in[7];

    const int E = in_sizes[7] / 2;          // 1,600,000
    const int* src = ei;
    const int* dst = ei + E;

    float* out = (float*)d_out;

    // ---- workspace layout ----
    char* wsb = (char*)d_ws;
    size_t p = 0;
    int* deg      = (int*)(wsb + p); p += ((size_t)NN * 4 + 1023) & ~1023ull;
    int* offsets  = (int*)(wsb + p); p += ((size_t)(NN + 1) * 4 + 1023) & ~1023ull;
    int* chunkSum = (int*)(wsb + p); p += 4096;
    int* chunkOff = (int*)(wsb + p); p += 4096;
    int* csr      = (int*)(wsb + p); p += ((size_t)E * 4 + 1023) & ~1023ull;
    int* rank     = (int*)(wsb + p); p += ((size_t)E * 4 + 1023) & ~1023ull;
    float* dinv   = (float*)(wsb + p); p += ((size_t)NN * 4 + 1023) & ~1023ull;
    __half* g     = (__half*)(wsb + p); p += (size_t)NN * DD * 2;

    const int NB = (NN + SCAN_CHUNK - 1) / SCAN_CHUNK;   // 49

    // ---- CSR build + dinv ----
    hipMemsetAsync(deg, 0, (size_t)NN * 4, stream);
    hist_rank_kernel<<<(E / 4 + 256) / 256 + 1, 256, 0, stream>>>(dst, E, deg, rank);
    scan1_kernel<<<NB, 256, 0, stream>>>(deg, chunkSum, dinv, NN);
    scan2_kernel<<<1, 512, 0, stream>>>(chunkSum, chunkOff, NB, offsets);
    scan3_kernel<<<NB, 256, 0, stream>>>(deg, chunkOff, offsets, NN);
    fill_kernel<<<(E / 4 + 256) / 256 + 1, 256, 0, stream>>>(src, dst, rank, E, offsets, csr);

    const int gemm_grid = (NN + 127) / 128;               // 782
    const int agg_grid  = ((size_t)NN * 64 + 255) / 256;  // 25000

    // ---- layer 1 ----
    gemm_norm_kernel<<<gemm_grid, 256, 0, stream>>>(x, W1, dinv, g);
    agg_kernel<<<agg_grid, 256, 0, stream>>>(g, dinv, offsets, csr, b1, out);
    // ---- layer 2 ----
    gemm_norm_kernel<<<gemm_grid, 256, 0, stream>>>(out, W2, dinv, g);
    agg_kernel<<<agg_grid, 256, 0, stream>>>(g, dinv, offsets, csr, b2, out);
    // ---- layer 3 ----
    gemm_norm_kernel<<<gemm_grid, 256, 0, stream>>>(out, W3, dinv, g);
    agg_kernel<<<agg_grid, 256, 0, stream>>>(g, dinv, offsets, csr, b3, out);
}